// Round 1
// baseline (7977.954 us; speedup 1.0000x reference)
//
#include <hip/hip_runtime.h>
#include <math.h>

#define LRELU 0.1f
#define SQRT_HALF 0.7071067811865476f

constexpr int T_LEN = 16384;
constexpr int TT = 64;      // positions per block tile
constexpr int KC = 8;       // i-chunk for conv staging

// ---------------- weight pre-transpose ----------------
// wT[li][k][i][o]  (o in [0,256)) from wn_ws[li][o][i][k]
// skT[li][i][o]    from sk_ws[li][o][i]
// o1T[i][o], o2T[i][o] from out{1,2}_w[o][i]
__global__ void prep_w(const float* __restrict__ wn_ws, const float* __restrict__ sk_ws,
                       const float* __restrict__ o1w, const float* __restrict__ o2w,
                       float* __restrict__ wT, float* __restrict__ skT,
                       float* __restrict__ o1T, float* __restrict__ o2T)
{
    int idx = blockIdx.x * 256 + threadIdx.x;
    if (idx < 2949120) {
        int o = idx & 255; int r = idx >> 8;
        int i = r & 127;   int r2 = r >> 7;
        int k = r2 % 3;    int li = r2 / 3;
        wT[idx] = wn_ws[(((size_t)li * 256 + o) * 128 + i) * 3 + k];
    } else if (idx < 2949120 + 491520) {
        int j = idx - 2949120;
        int o = j & 127; int r = j >> 7;
        int i = r & 127; int li = r >> 7;
        skT[j] = sk_ws[((size_t)li * 128 + o) * 128 + i];
    } else if (idx < 2949120 + 491520 + 16384) {
        int j = idx - (2949120 + 491520);
        int o = j & 127; int i = j >> 7;
        o1T[j] = o1w[o * 128 + i];
    } else if (idx < 2949120 + 491520 + 32768) {
        int j = idx - (2949120 + 491520 + 16384);
        int o = j & 127; int i = j >> 7;
        o2T[j] = o2w[o * 128 + i];
    }
}

// ---------------- front end ----------------
// x64[n][o][t] = b[o] + sum_i in_w[o][i] * mel[n][i][t]
__global__ void fe_in(const float* __restrict__ mel, const float* __restrict__ w,
                      const float* __restrict__ b, float* __restrict__ out)
{
    __shared__ float mc[80];
    int t = blockIdx.x, n = blockIdx.y, o = threadIdx.x;
    if (o < 80) mc[o] = mel[(n * 80 + o) * 64 + t];
    __syncthreads();
    float acc = b[o];
    #pragma unroll 8
    for (int i = 0; i < 80; i++) acc = fmaf(w[o * 80 + i], mc[i], acc);
    out[((size_t)n * 128 + o) * 64 + t] = acc;
}

// pre dilated conv + leaky + residual*sqrt(0.5)
__global__ void fe_pre(const float* __restrict__ in, float* __restrict__ out,
                       const float* __restrict__ w, const float* __restrict__ b, int d)
{
    __shared__ float col[3][128];
    int t = blockIdx.x, n = blockIdx.y, o = threadIdx.x;
    #pragma unroll
    for (int s = 0; s < 3; s++) {
        int tt = t + (s - 1) * d;
        col[s][o] = ((unsigned)tt < 64u) ? in[(n * 128 + o) * 64 + tt] : 0.f;
    }
    __syncthreads();
    float acc = b[o];
    const float* wo = w + o * 384;
    #pragma unroll 4
    for (int i = 0; i < 128; i++) {
        acc = fmaf(wo[i * 3 + 0], col[0][i], acc);
        acc = fmaf(wo[i * 3 + 1], col[1][i], acc);
        acc = fmaf(wo[i * 3 + 2], col[2][i], acc);
    }
    float y = acc > 0.f ? acc : LRELU * acc;
    out[(n * 128 + o) * 64 + t] = (y + in[(n * 128 + o) * 64 + t]) * SQRT_HALF;
}

// transpose conv k=4 s=4: y[n][o][4q+r] = leaky(b[o] + sum_i w[o][i][3-r]*x[n][i][q])
__global__ void fe_up(const float* __restrict__ in, float* __restrict__ out,
                      const float* __restrict__ w, const float* __restrict__ b, int Lin)
{
    __shared__ float col[128];
    int t = blockIdx.x, n = blockIdx.y, o = threadIdx.x;
    int q = t >> 2, r = t & 3;
    col[o] = in[((size_t)n * 128 + o) * Lin + q];
    __syncthreads();
    float acc = b[o];
    const float* wo = w + o * 512 + (3 - r);
    #pragma unroll 8
    for (int i = 0; i < 128; i++) acc = fmaf(wo[i * 4], col[i], acc);
    out[((size_t)n * 128 + o) * (size_t)(4 * Lin) + t] = acc > 0.f ? acc : LRELU * acc;
}

// 16x repeat + zero skips
__global__ void fe_repeat(const float* __restrict__ x1024, float* __restrict__ X,
                          float* __restrict__ S)
{
    size_t idx = (size_t)blockIdx.x * 256 + threadIdx.x; // 8388608 total
    int t = (int)(idx & 16383);
    size_t r = idx >> 14; // n*128+c
    X[idx] = x1024[r * 1024 + (t >> 4)];
    S[idx] = 0.f;
}

// ---------------- fused WaveNet layer ----------------
// phase1: g[256][TT] = dilated conv;  gated = tanh(lo)*sigmoid(hi) -> LDS
// phase2: s = skw * gated;  x_out = s + x_in;  skips += s
__global__ __launch_bounds__(256, 2)
void wn_layer(const float* __restrict__ Xin, float* __restrict__ Xout,
              float* __restrict__ Skips,
              const float* __restrict__ wT,   // [3][128][256]
              const float* __restrict__ gb,   // [256]
              const float* __restrict__ skT,  // [128][128] i-major
              const float* __restrict__ skb,  // [128]
              int dil)
{
    __shared__ float gt[128][TT];                              // 32 KB
    __shared__ float regA[3 * KC * 256 + 3 * KC * TT];         // 30 KB (ws|xs), reused as skws
    float (*ws)[KC][256] = (float(*)[KC][256])regA;
    float (*xs)[KC][TT]  = (float(*)[KC][TT])(regA + 3 * KC * 256);
    float (*skws)[128]   = (float(*)[128])regA;

    const int n = blockIdx.y;
    const int t0 = blockIdx.x * TT;
    const int tid = threadIdx.x;
    const int tg = tid & 7;    // 8 t-groups x 8 positions
    const int pg = tid >> 3;   // 32 pair-groups x 4 pairs

    const float* Xn = Xin + (size_t)n * 128 * T_LEN;

    float acc_lo[4][8], acc_hi[4][8];
    #pragma unroll
    for (int a = 0; a < 4; a++)
        #pragma unroll
        for (int b = 0; b < 8; b++) { acc_lo[a][b] = 0.f; acc_hi[a][b] = 0.f; }

    for (int ic = 0; ic < 128; ic += KC) {
        // stage weights: 3*KC*256 floats
        float* wsf = regA;
        for (int j = tid * 4; j < 3 * KC * 256; j += 256 * 4) {
            int s = j >> 11;            // /(KC*256)
            int kk = (j >> 8) & (KC - 1);
            int o = j & 255;
            *reinterpret_cast<float4*>(wsf + j) =
                *reinterpret_cast<const float4*>(wT + (((s * 128) + ic + kk) << 8) + o);
        }
        // stage x slabs (3 shifts)
        float* xsf = regA + 3 * KC * 256;
        for (int j = tid; j < 3 * KC * TT; j += 256) {
            int s = j / (KC * TT);
            int r = j - s * (KC * TT);
            int kk = r >> 6; int tt = r & 63;
            int t = t0 + tt + (s - 1) * dil;
            float v = 0.f;
            if ((unsigned)t < (unsigned)T_LEN) v = Xn[(size_t)(ic + kk) * T_LEN + t];
            xsf[j] = v;
        }
        __syncthreads();
        #pragma unroll
        for (int kk = 0; kk < KC; kk++) {
            #pragma unroll
            for (int s = 0; s < 3; s++) {
                float4 wlo = *reinterpret_cast<const float4*>(&ws[s][kk][pg * 4]);
                float4 whi = *reinterpret_cast<const float4*>(&ws[s][kk][128 + pg * 4]);
                float4 xa = *reinterpret_cast<const float4*>(&xs[s][kk][tg * 8]);
                float4 xb = *reinterpret_cast<const float4*>(&xs[s][kk][tg * 8 + 4]);
                float xv[8] = {xa.x, xa.y, xa.z, xa.w, xb.x, xb.y, xb.z, xb.w};
                float wl[4] = {wlo.x, wlo.y, wlo.z, wlo.w};
                float wh[4] = {whi.x, whi.y, whi.z, whi.w};
                #pragma unroll
                for (int a = 0; a < 4; a++)
                    #pragma unroll
                    for (int b = 0; b < 8; b++) {
                        acc_lo[a][b] = fmaf(wl[a], xv[b], acc_lo[a][b]);
                        acc_hi[a][b] = fmaf(wh[a], xv[b], acc_hi[a][b]);
                    }
            }
        }
        __syncthreads();
    }

    // gating -> LDS
    #pragma unroll
    for (int a = 0; a < 4; a++) {
        int p = pg * 4 + a;
        float blo = gb[p], bhi = gb[128 + p];
        #pragma unroll
        for (int b = 0; b < 8; b++) {
            float glo = acc_lo[a][b] + blo;
            float ghi = acc_hi[a][b] + bhi;
            gt[p][tg * 8 + b] = tanhf(glo) * (1.f / (1.f + expf(-ghi)));
        }
    }
    __syncthreads();

    // phase 2: 1x1 skip conv
    float acc2[4][8];
    #pragma unroll
    for (int a = 0; a < 4; a++)
        #pragma unroll
        for (int b = 0; b < 8; b++) acc2[a][b] = 0.f;

    for (int ic = 0; ic < 128; ic += 16) {
        for (int j = tid * 4; j < 16 * 128; j += 256 * 4) {
            int kk = j >> 7; int o = j & 127;
            *reinterpret_cast<float4*>(&skws[kk][o]) =
                *reinterpret_cast<const float4*>(skT + ((ic + kk) << 7) + o);
        }
        __syncthreads();
        #pragma unroll
        for (int kk = 0; kk < 16; kk++) {
            float4 wv = *reinterpret_cast<const float4*>(&skws[kk][pg * 4]);
            float4 ga = *reinterpret_cast<const float4*>(&gt[ic + kk][tg * 8]);
            float4 gbv = *reinterpret_cast<const float4*>(&gt[ic + kk][tg * 8 + 4]);
            float xv[8] = {ga.x, ga.y, ga.z, ga.w, gbv.x, gbv.y, gbv.z, gbv.w};
            float wl[4] = {wv.x, wv.y, wv.z, wv.w};
            #pragma unroll
            for (int a = 0; a < 4; a++)
                #pragma unroll
                for (int b = 0; b < 8; b++)
                    acc2[a][b] = fmaf(wl[a], xv[b], acc2[a][b]);
        }
        __syncthreads();
    }

    // epilogue: x_out = s + x_in ; skips += s
    float* Xo = Xout + (size_t)n * 128 * T_LEN;
    float* Sk = Skips + (size_t)n * 128 * T_LEN;
    #pragma unroll
    for (int a = 0; a < 4; a++) {
        int o = pg * 4 + a;
        float bo = skb[o];
        size_t base = (size_t)o * T_LEN + t0 + tg * 8;
        #pragma unroll
        for (int h = 0; h < 2; h++) {
            float4 xr = *reinterpret_cast<const float4*>(Xn + base + h * 4);
            float4 sk = *reinterpret_cast<const float4*>(Sk + base + h * 4);
            float4 sv;
            sv.x = acc2[a][h * 4 + 0] + bo;
            sv.y = acc2[a][h * 4 + 1] + bo;
            sv.z = acc2[a][h * 4 + 2] + bo;
            sv.w = acc2[a][h * 4 + 3] + bo;
            float4 xw = {sv.x + xr.x, sv.y + xr.y, sv.z + xr.z, sv.w + xr.w};
            float4 sw = {sk.x + sv.x, sk.y + sv.y, sk.z + sv.z, sk.w + sv.w};
            *reinterpret_cast<float4*>(Xo + base + h * 4) = xw;
            *reinterpret_cast<float4*>(Sk + base + h * 4) = sw;
        }
    }
}

// ---------------- output stack 1x1 convs ----------------
template<bool RELU_IN>
__global__ __launch_bounds__(256, 2)
void os_conv(const float* __restrict__ In0, float* __restrict__ Out,
             const float* __restrict__ wTr, const float* __restrict__ bias)
{
    __shared__ float xt[128][TT];   // 32 KB
    __shared__ float wsk[16][128];  // 8 KB
    const int n = blockIdx.y, t0 = blockIdx.x * TT;
    const int tid = threadIdx.x, tg = tid & 7, pg = tid >> 3;
    const float* In = In0 + (size_t)n * 128 * T_LEN;

    for (int j = tid * 4; j < 128 * TT; j += 256 * 4) {
        int i = j >> 6, tt = j & 63;
        float4 v = *reinterpret_cast<const float4*>(In + (size_t)i * T_LEN + t0 + tt);
        if (RELU_IN) {
            v.x = fmaxf(v.x, 0.f); v.y = fmaxf(v.y, 0.f);
            v.z = fmaxf(v.z, 0.f); v.w = fmaxf(v.w, 0.f);
        }
        *reinterpret_cast<float4*>(&xt[i][tt]) = v;
    }
    float acc[4][8];
    #pragma unroll
    for (int a = 0; a < 4; a++)
        #pragma unroll
        for (int b = 0; b < 8; b++) acc[a][b] = 0.f;
    __syncthreads();

    for (int ic = 0; ic < 128; ic += 16) {
        for (int j = tid * 4; j < 16 * 128; j += 256 * 4) {
            int kk = j >> 7; int o = j & 127;
            *reinterpret_cast<float4*>(&wsk[kk][o]) =
                *reinterpret_cast<const float4*>(wTr + ((ic + kk) << 7) + o);
        }
        __syncthreads();
        #pragma unroll
        for (int kk = 0; kk < 16; kk++) {
            float4 wv = *reinterpret_cast<const float4*>(&wsk[kk][pg * 4]);
            float4 ga = *reinterpret_cast<const float4*>(&xt[ic + kk][tg * 8]);
            float4 gbv = *reinterpret_cast<const float4*>(&xt[ic + kk][tg * 8 + 4]);
            float xv[8] = {ga.x, ga.y, ga.z, ga.w, gbv.x, gbv.y, gbv.z, gbv.w};
            float wl[4] = {wv.x, wv.y, wv.z, wv.w};
            #pragma unroll
            for (int a = 0; a < 4; a++)
                #pragma unroll
                for (int b = 0; b < 8; b++)
                    acc[a][b] = fmaf(wl[a], xv[b], acc[a][b]);
        }
        __syncthreads();
    }

    float* Op = Out + (size_t)n * 128 * T_LEN;
    #pragma unroll
    for (int a = 0; a < 4; a++) {
        int o = pg * 4 + a;
        float bo = bias[o];
        size_t base = (size_t)o * T_LEN + t0 + tg * 8;
        #pragma unroll
        for (int h = 0; h < 2; h++) {
            float4 v;
            v.x = fmaxf(acc[a][h * 4 + 0] + bo, 0.f);
            v.y = fmaxf(acc[a][h * 4 + 1] + bo, 0.f);
            v.z = fmaxf(acc[a][h * 4 + 2] + bo, 0.f);
            v.w = fmaxf(acc[a][h * 4 + 3] + bo, 0.f);
            *reinterpret_cast<float4*>(Op + base + h * 4) = v;
        }
    }
}

__global__ void os_final(const float* __restrict__ in, const float* __restrict__ w,
                         const float* __restrict__ b, float* __restrict__ out)
{
    int idx = blockIdx.x * 256 + threadIdx.x; // 65536 = n*16384+t
    int n = idx >> 14; int t = idx & 16383;
    const float* In = in + (size_t)n * 128 * T_LEN + t;
    float acc = b[0];
    #pragma unroll 4
    for (int i = 0; i < 128; i++) acc = fmaf(w[i], In[(size_t)i * T_LEN], acc);
    out[idx] = tanhf(acc);
}

// ---------------- launch ----------------
extern "C" void kernel_launch(void* const* d_in, const int* in_sizes, int n_in,
                              void* d_out, int out_size, void* d_ws, size_t ws_size,
                              hipStream_t stream)
{
    (void)in_sizes; (void)n_in; (void)out_size; (void)ws_size;
    const float* mel    = (const float*)d_in[0];
    const float* in_w   = (const float*)d_in[1];
    const float* in_b   = (const float*)d_in[2];
    const float* pre_w  = (const float*)d_in[3];
    const float* pre_b  = (const float*)d_in[4];
    const float* up1_w  = (const float*)d_in[5];
    const float* up1_b  = (const float*)d_in[6];
    const float* up2_w  = (const float*)d_in[7];
    const float* up2_b  = (const float*)d_in[8];
    const float* wn_wsp = (const float*)d_in[9];
    const float* wn_bs  = (const float*)d_in[10];
    const float* sk_wsp = (const float*)d_in[11];
    const float* sk_bs  = (const float*)d_in[12];
    const float* o1w = (const float*)d_in[13];
    const float* o1b = (const float*)d_in[14];
    const float* o2w = (const float*)d_in[15];
    const float* o2b = (const float*)d_in[16];
    const float* o3w = (const float*)d_in[17];
    const float* o3b = (const float*)d_in[18];

    float* wsf = (float*)d_ws;
    float* X0   = wsf;                  // 8388608
    float* X1   = X0 + 8388608;
    float* SK   = X1 + 8388608;
    float* wT   = SK + 8388608;         // 2949120
    float* skT  = wT + 2949120;         // 491520
    float* o1T  = skT + 491520;         // 16384
    float* o2T  = o1T + 16384;          // 16384
    float* a64  = o2T + 16384;          // 32768
    float* b64  = a64 + 32768;          // 32768
    float* x256 = b64 + 32768;          // 131072
    float* x1024= x256 + 131072;        // 524288

    prep_w<<<13568, 256, 0, stream>>>(wn_wsp, sk_wsp, o1w, o2w, wT, skT, o1T, o2T);

    fe_in<<<dim3(64, 4), 128, 0, stream>>>(mel, in_w, in_b, a64);
    fe_pre<<<dim3(64, 4), 128, 0, stream>>>(a64, b64, pre_w + 0 * 49152, pre_b + 0 * 128, 1);
    fe_pre<<<dim3(64, 4), 128, 0, stream>>>(b64, a64, pre_w + 1 * 49152, pre_b + 1 * 128, 2);
    fe_pre<<<dim3(64, 4), 128, 0, stream>>>(a64, b64, pre_w + 2 * 49152, pre_b + 2 * 128, 4);
    fe_pre<<<dim3(64, 4), 128, 0, stream>>>(b64, a64, pre_w + 3 * 49152, pre_b + 3 * 128, 8);
    fe_pre<<<dim3(64, 4), 128, 0, stream>>>(a64, b64, pre_w + 4 * 49152, pre_b + 4 * 128, 16);
    fe_up<<<dim3(256, 4), 128, 0, stream>>>(b64, x256, up1_w, up1_b, 64);
    fe_up<<<dim3(1024, 4), 128, 0, stream>>>(x256, x1024, up2_w, up2_b, 256);
    fe_repeat<<<32768, 256, 0, stream>>>(x1024, X0, SK);

    float* xc = X0; float* xn = X1;
    for (int li = 0; li < 30; li++) {
        int d = 1 << (li % 10);
        wn_layer<<<dim3(T_LEN / TT, 4), 256, 0, stream>>>(
            xc, xn, SK,
            wT + (size_t)li * 3 * 128 * 256, wn_bs + li * 256,
            skT + (size_t)li * 128 * 128, sk_bs + li * 128, d);
        float* tmp = xc; xc = xn; xn = tmp;
    }

    os_conv<true><<<dim3(T_LEN / TT, 4), 256, 0, stream>>>(SK, X0, o1T, o1b);
    os_conv<false><<<dim3(T_LEN / TT, 4), 256, 0, stream>>>(X0, X1, o2T, o2b);
    os_final<<<256, 256, 0, stream>>>(X1, o3w, o3b, (float*)d_out);
}

// Round 2
// 2913.234 us; speedup vs baseline: 2.7385x; 2.7385x over previous
//
#include <hip/hip_runtime.h>
#include <math.h>

#define LRELU 0.1f
#define SQRT_HALF 0.7071067811865476f

constexpr int T_LEN = 16384;
constexpr int TT = 64;      // os_conv tile

typedef __attribute__((ext_vector_type(8))) short short8;
typedef __attribute__((ext_vector_type(4))) float f32x4;

// split f32 -> bf16 hi + bf16 lo (RNE)
__device__ __host__ inline void bsplit(float v, short& hi, short& lo) {
    unsigned u = __float_as_uint(v);
    unsigned rh = (u + 0x7FFFu + ((u >> 16) & 1u)) >> 16;
    float fh = __uint_as_float(rh << 16);
    float r = v - fh;
    unsigned u2 = __float_as_uint(r);
    unsigned rl = (u2 + 0x7FFFu + ((u2 >> 16) & 1u)) >> 16;
    hi = (short)rh; lo = (short)rl;
}

// ---------------- weight packing ----------------
// Apk[li][ks 12][m16 16][h 2][lane 64][j 8]  (conv weights, bf16 hi/lo)
//   A[o][k], k = tap*128 + i ; frag: m = lane&15, k_local = 4*(lane>>4)+(j&3)+16*(j>>2)
// Spk[li][ks2 4][m8 8][h 2][lane 64][j 8]    (skip weights)
constexpr int NA_ELEMS = 30 * 12 * 16 * 2 * 64 * 8;  // 5,898,240
constexpr int NS_ELEMS = 30 * 4 * 8 * 2 * 64 * 8;    //   983,040

__global__ void prep_w(const float* __restrict__ wn_ws, const float* __restrict__ sk_ws,
                       const float* __restrict__ o1w, const float* __restrict__ o2w,
                       short* __restrict__ Apk, short* __restrict__ Spk,
                       float* __restrict__ o1T, float* __restrict__ o2T)
{
    int idx = blockIdx.x * 256 + threadIdx.x;
    if (idx < NA_ELEMS) {
        int j = idx & 7;  int t1 = idx >> 3;
        int l = t1 & 63;  int t2 = t1 >> 6;
        int h = t2 & 1;   int t3 = t2 >> 1;
        int m16 = t3 & 15; int t4 = t3 >> 4;
        int ks = t4 % 12; int li = t4 / 12;
        int o = m16 * 16 + (l & 15);
        int k = ks * 32 + 4 * (l >> 4) + (j & 3) + 16 * (j >> 2);
        int tap = k >> 7, i = k & 127;
        float v = wn_ws[(((size_t)li * 256 + o) * 128 + i) * 3 + tap];
        short hi, lo; bsplit(v, hi, lo);
        Apk[idx] = h ? lo : hi;
    } else if (idx < NA_ELEMS + NS_ELEMS) {
        int jdx = idx - NA_ELEMS;
        int j = jdx & 7;  int t1 = jdx >> 3;
        int l = t1 & 63;  int t2 = t1 >> 6;
        int h = t2 & 1;   int t3 = t2 >> 1;
        int m8 = t3 & 7;  int t4 = t3 >> 3;
        int ks2 = t4 & 3; int li = t4 >> 2;
        int o = m8 * 16 + (l & 15);
        int i = ks2 * 32 + 4 * (l >> 4) + (j & 3) + 16 * (j >> 2);
        float v = sk_ws[((size_t)li * 128 + o) * 128 + i];
        short hi, lo; bsplit(v, hi, lo);
        Spk[jdx] = h ? lo : hi;
    } else if (idx < NA_ELEMS + NS_ELEMS + 16384) {
        int j = idx - (NA_ELEMS + NS_ELEMS);
        int o = j & 127; int i = j >> 7;
        o1T[j] = o1w[o * 128 + i];
    } else if (idx < NA_ELEMS + NS_ELEMS + 32768) {
        int j = idx - (NA_ELEMS + NS_ELEMS + 16384);
        int o = j & 127; int i = j >> 7;
        o2T[j] = o2w[o * 128 + i];
    }
}

// ---------------- front end (round-1, small) ----------------
__global__ void fe_in(const float* __restrict__ mel, const float* __restrict__ w,
                      const float* __restrict__ b, float* __restrict__ out)
{
    __shared__ float mc[80];
    int t = blockIdx.x, n = blockIdx.y, o = threadIdx.x;
    if (o < 80) mc[o] = mel[(n * 80 + o) * 64 + t];
    __syncthreads();
    float acc = b[o];
    #pragma unroll 8
    for (int i = 0; i < 80; i++) acc = fmaf(w[o * 80 + i], mc[i], acc);
    out[((size_t)n * 128 + o) * 64 + t] = acc;
}

__global__ void fe_pre(const float* __restrict__ in, float* __restrict__ out,
                       const float* __restrict__ w, const float* __restrict__ b, int d)
{
    __shared__ float col[3][128];
    int t = blockIdx.x, n = blockIdx.y, o = threadIdx.x;
    #pragma unroll
    for (int s = 0; s < 3; s++) {
        int tt = t + (s - 1) * d;
        col[s][o] = ((unsigned)tt < 64u) ? in[(n * 128 + o) * 64 + tt] : 0.f;
    }
    __syncthreads();
    float acc = b[o];
    const float* wo = w + o * 384;
    #pragma unroll 4
    for (int i = 0; i < 128; i++) {
        acc = fmaf(wo[i * 3 + 0], col[0][i], acc);
        acc = fmaf(wo[i * 3 + 1], col[1][i], acc);
        acc = fmaf(wo[i * 3 + 2], col[2][i], acc);
    }
    float y = acc > 0.f ? acc : LRELU * acc;
    out[(n * 128 + o) * 64 + t] = (y + in[(n * 128 + o) * 64 + t]) * SQRT_HALF;
}

__global__ void fe_up(const float* __restrict__ in, float* __restrict__ out,
                      const float* __restrict__ w, const float* __restrict__ b, int Lin)
{
    __shared__ float col[128];
    int t = blockIdx.x, n = blockIdx.y, o = threadIdx.x;
    int q = t >> 2, r = t & 3;
    col[o] = in[((size_t)n * 128 + o) * Lin + q];
    __syncthreads();
    float acc = b[o];
    const float* wo = w + o * 512 + (3 - r);
    #pragma unroll 8
    for (int i = 0; i < 128; i++) acc = fmaf(wo[i * 4], col[i], acc);
    out[((size_t)n * 128 + o) * (size_t)(4 * Lin) + t] = acc > 0.f ? acc : LRELU * acc;
}

__global__ void fe_repeat(const float* __restrict__ x1024, float* __restrict__ X,
                          float* __restrict__ S)
{
    size_t idx = (size_t)blockIdx.x * 256 + threadIdx.x;
    int t = (int)(idx & 16383);
    size_t r = idx >> 14;
    X[idx] = x1024[r * 1024 + (t >> 4)];
    S[idx] = 0.f;
}

// ---------------- fused WaveNet layer (MFMA bf16-split) ----------------
// tile: all 256 gate channels x 128 positions, 4 waves
// wave w owns gate pairs (ch, ch+128) for ch in [32w,32w+32)  -> conv m16 frags {2w,2w+1,8+2w,8+2w+1}
// and skip out channels [32w,32w+32) -> m8 frags {2w,2w+1}
__global__ __launch_bounds__(256, 2)
void wn_layer(const float* __restrict__ Xin, float* __restrict__ Xout,
              float* __restrict__ Skips,
              const short* __restrict__ Apk,   // [12][16][2][64][8]
              const float* __restrict__ gb,    // [256]
              const short* __restrict__ Spk,   // [4][8][2][64][8]
              const float* __restrict__ skb,   // [128]
              int dil)
{
    __shared__ short Bbuf[2 * 8 * 64 * 8];     // 16 KB  [h][f][lane][j]
    __shared__ short Gbuf[4 * 2 * 8 * 64 * 8]; // 64 KB  [ks2][h][f][lane][j]

    const int n = blockIdx.y;
    const int t0 = blockIdx.x * 128;
    const int tid = threadIdx.x;
    const int lane = tid & 63;
    const int w = tid >> 6;

    const float* Xn = Xin + (size_t)n * 128 * T_LEN;

    f32x4 acc[4][8];
    const f32x4 z4 = {0.f, 0.f, 0.f, 0.f};
    #pragma unroll
    for (int mf = 0; mf < 4; mf++)
        #pragma unroll
        for (int nf = 0; nf < 8; nf++) acc[mf][nf] = z4;

    const int m16c[4] = {2 * w, 2 * w + 1, 8 + 2 * w, 8 + 2 * w + 1};
    const short8* ap = (const short8*)Apk;

    for (int ks = 0; ks < 12; ks++) {
        const int s = ks >> 2;
        const int i0 = (ks & 3) * 32;
        const int tsh = t0 + (s - 1) * dil;
        // ---- stage x slab [32 ch][128 t] as hi/lo bf16 in B-frag layout ----
        #pragma unroll
        for (int p = 0; p < 4; p++) {
            int kk = (tid >> 5) + p * 8;
            const float* src = Xn + (size_t)(i0 + kk) * T_LEN;
            int ttb = (tid & 31) * 4;
            int j = (kk & 3) + 4 * (kk >> 4);
            int g = (kk >> 2) & 3;
            #pragma unroll
            for (int e = 0; e < 4; e++) {
                int tt = ttb + e;
                int t = tsh + tt;
                float v = ((unsigned)t < (unsigned)T_LEN) ? src[t] : 0.f;
                short hi, lo; bsplit(v, hi, lo);
                int base = (((tt >> 4) * 64) + (tt & 15) + 16 * g) * 8 + j;
                Bbuf[base] = hi;
                Bbuf[4096 + base] = lo;
            }
        }
        __syncthreads();
        short8 Ah[4], Al[4];
        #pragma unroll
        for (int mf = 0; mf < 4; mf++) {
            Ah[mf] = ap[((ks * 16 + m16c[mf]) * 2 + 0) * 64 + lane];
            Al[mf] = ap[((ks * 16 + m16c[mf]) * 2 + 1) * 64 + lane];
        }
        #pragma unroll
        for (int nf = 0; nf < 8; nf++) {
            short8 Bh = *(const short8*)&Bbuf[(nf * 64 + lane) * 8];
            short8 Bl = *(const short8*)&Bbuf[4096 + (nf * 64 + lane) * 8];
            #pragma unroll
            for (int mf = 0; mf < 4; mf++) {
                acc[mf][nf] = __builtin_amdgcn_mfma_f32_16x16x32_bf16(Ah[mf], Bh, acc[mf][nf], 0, 0, 0);
                acc[mf][nf] = __builtin_amdgcn_mfma_f32_16x16x32_bf16(Al[mf], Bh, acc[mf][nf], 0, 0, 0);
                acc[mf][nf] = __builtin_amdgcn_mfma_f32_16x16x32_bf16(Ah[mf], Bl, acc[mf][nf], 0, 0, 0);
            }
        }
        __syncthreads();
    }

    // ---- gating: gated = tanh(g_lo)*sigmoid(g_hi), write to Gbuf (skip B operand) ----
    const int rowoff = 4 * (lane >> 4);
    float bt[2][4], bs[2][4];
    #pragma unroll
    for (int mf2 = 0; mf2 < 2; mf2++)
        #pragma unroll
        for (int r = 0; r < 4; r++) {
            int ch = (2 * w + mf2) * 16 + rowoff + r;
            bt[mf2][r] = gb[ch];
            bs[mf2][r] = gb[128 + ch];
        }
    #pragma unroll
    for (int nf = 0; nf < 8; nf++) {
        short8 hv, lv;
        #pragma unroll
        for (int mf2 = 0; mf2 < 2; mf2++)
            #pragma unroll
            for (int r = 0; r < 4; r++) {
                float g1 = acc[mf2][nf][r] + bt[mf2][r];
                float g2 = acc[mf2 + 2][nf][r] + bs[mf2][r];
                float gv = tanhf(g1) * (1.f / (1.f + expf(-g2)));
                short hi, lo; bsplit(gv, hi, lo);
                hv[4 * mf2 + r] = hi;
                lv[4 * mf2 + r] = lo;
            }
        *(short8*)&Gbuf[((w * 2 + 0) * 8 + nf) * 512 + lane * 8] = hv;
        *(short8*)&Gbuf[((w * 2 + 1) * 8 + nf) * 512 + lane * 8] = lv;
    }
    __syncthreads();

    // ---- skip 1x1 GEMM: s[o][t], o in [32w,32w+32) ----
    f32x4 acc2[2][8];
    #pragma unroll
    for (int mf2 = 0; mf2 < 2; mf2++)
        #pragma unroll
        for (int nf = 0; nf < 8; nf++) acc2[mf2][nf] = z4;

    const short8* sp = (const short8*)Spk;
    #pragma unroll
    for (int ks2 = 0; ks2 < 4; ks2++) {
        short8 A2h[2], A2l[2];
        #pragma unroll
        for (int mf2 = 0; mf2 < 2; mf2++) {
            int m8 = 2 * w + mf2;
            A2h[mf2] = sp[((ks2 * 8 + m8) * 2 + 0) * 64 + lane];
            A2l[mf2] = sp[((ks2 * 8 + m8) * 2 + 1) * 64 + lane];
        }
        #pragma unroll
        for (int nf = 0; nf < 8; nf++) {
            short8 Bh = *(const short8*)&Gbuf[((ks2 * 2 + 0) * 8 + nf) * 512 + lane * 8];
            short8 Bl = *(const short8*)&Gbuf[((ks2 * 2 + 1) * 8 + nf) * 512 + lane * 8];
            #pragma unroll
            for (int mf2 = 0; mf2 < 2; mf2++) {
                acc2[mf2][nf] = __builtin_amdgcn_mfma_f32_16x16x32_bf16(A2h[mf2], Bh, acc2[mf2][nf], 0, 0, 0);
                acc2[mf2][nf] = __builtin_amdgcn_mfma_f32_16x16x32_bf16(A2l[mf2], Bh, acc2[mf2][nf], 0, 0, 0);
                acc2[mf2][nf] = __builtin_amdgcn_mfma_f32_16x16x32_bf16(A2h[mf2], Bl, acc2[mf2][nf], 0, 0, 0);
            }
        }
    }

    // ---- epilogue: s += bias; Xout = s + Xin; Skips += s ----
    float* Xo = Xout + (size_t)n * 128 * T_LEN;
    float* Sk = Skips + (size_t)n * 128 * T_LEN;
    #pragma unroll
    for (int mf2 = 0; mf2 < 2; mf2++) {
        #pragma unroll
        for (int r = 0; r < 4; r++) {
            int o = (2 * w + mf2) * 16 + rowoff + r;
            float bo = skb[o];
            size_t rowbase = (size_t)o * T_LEN + t0 + (lane & 15);
            #pragma unroll
            for (int nf = 0; nf < 8; nf++) {
                size_t adr = rowbase + nf * 16;
                float sv = acc2[mf2][nf][r] + bo;
                Xo[adr] = sv + Xn[adr];
                Sk[adr] = Sk[adr] + sv;
            }
        }
    }
}

// ---------------- output stack ----------------
template<bool RELU_IN>
__global__ __launch_bounds__(256, 2)
void os_conv(const float* __restrict__ In0, float* __restrict__ Out,
             const float* __restrict__ wTr, const float* __restrict__ bias)
{
    __shared__ float xt[128][TT];
    __shared__ float wsk[16][128];
    const int n = blockIdx.y, t0 = blockIdx.x * TT;
    const int tid = threadIdx.x, tg = tid & 7, pg = tid >> 3;
    const float* In = In0 + (size_t)n * 128 * T_LEN;

    for (int j = tid * 4; j < 128 * TT; j += 256 * 4) {
        int i = j >> 6, tt = j & 63;
        float4 v = *reinterpret_cast<const float4*>(In + (size_t)i * T_LEN + t0 + tt);
        if (RELU_IN) {
            v.x = fmaxf(v.x, 0.f); v.y = fmaxf(v.y, 0.f);
            v.z = fmaxf(v.z, 0.f); v.w = fmaxf(v.w, 0.f);
        }
        *reinterpret_cast<float4*>(&xt[i][tt]) = v;
    }
    float acc[4][8];
    #pragma unroll
    for (int a = 0; a < 4; a++)
        #pragma unroll
        for (int b = 0; b < 8; b++) acc[a][b] = 0.f;
    __syncthreads();

    for (int ic = 0; ic < 128; ic += 16) {
        for (int j = tid * 4; j < 16 * 128; j += 256 * 4) {
            int kk = j >> 7; int o = j & 127;
            *reinterpret_cast<float4*>(&wsk[kk][o]) =
                *reinterpret_cast<const float4*>(wTr + ((ic + kk) << 7) + o);
        }
        __syncthreads();
        #pragma unroll
        for (int kk = 0; kk < 16; kk++) {
            float4 wv = *reinterpret_cast<const float4*>(&wsk[kk][pg * 4]);
            float4 ga = *reinterpret_cast<const float4*>(&xt[ic + kk][tg * 8]);
            float4 gbv = *reinterpret_cast<const float4*>(&xt[ic + kk][tg * 8 + 4]);
            float xv[8] = {ga.x, ga.y, ga.z, ga.w, gbv.x, gbv.y, gbv.z, gbv.w};
            float wl[4] = {wv.x, wv.y, wv.z, wv.w};
            #pragma unroll
            for (int a = 0; a < 4; a++)
                #pragma unroll
                for (int b = 0; b < 8; b++)
                    acc[a][b] = fmaf(wl[a], xv[b], acc[a][b]);
        }
        __syncthreads();
    }

    float* Op = Out + (size_t)n * 128 * T_LEN;
    #pragma unroll
    for (int a = 0; a < 4; a++) {
        int o = pg * 4 + a;
        float bo = bias[o];
        size_t base = (size_t)o * T_LEN + t0 + tg * 8;
        #pragma unroll
        for (int h = 0; h < 2; h++) {
            float4 v;
            v.x = fmaxf(acc[a][h * 4 + 0] + bo, 0.f);
            v.y = fmaxf(acc[a][h * 4 + 1] + bo, 0.f);
            v.z = fmaxf(acc[a][h * 4 + 2] + bo, 0.f);
            v.w = fmaxf(acc[a][h * 4 + 3] + bo, 0.f);
            *reinterpret_cast<float4*>(Op + base + h * 4) = v;
        }
    }
}

__global__ void os_final(const float* __restrict__ in, const float* __restrict__ w,
                         const float* __restrict__ b, float* __restrict__ out)
{
    int idx = blockIdx.x * 256 + threadIdx.x;
    int n = idx >> 14; int t = idx & 16383;
    const float* In = in + (size_t)n * 128 * T_LEN + t;
    float acc = b[0];
    #pragma unroll 4
    for (int i = 0; i < 128; i++) acc = fmaf(w[i], In[(size_t)i * T_LEN], acc);
    out[idx] = tanhf(acc);
}

// ---------------- launch ----------------
extern "C" void kernel_launch(void* const* d_in, const int* in_sizes, int n_in,
                              void* d_out, int out_size, void* d_ws, size_t ws_size,
                              hipStream_t stream)
{
    (void)in_sizes; (void)n_in; (void)out_size; (void)ws_size;
    const float* mel    = (const float*)d_in[0];
    const float* in_w   = (const float*)d_in[1];
    const float* in_b   = (const float*)d_in[2];
    const float* pre_w  = (const float*)d_in[3];
    const float* pre_b  = (const float*)d_in[4];
    const float* up1_w  = (const float*)d_in[5];
    const float* up1_b  = (const float*)d_in[6];
    const float* up2_w  = (const float*)d_in[7];
    const float* up2_b  = (const float*)d_in[8];
    const float* wn_wsp = (const float*)d_in[9];
    const float* wn_bs  = (const float*)d_in[10];
    const float* sk_wsp = (const float*)d_in[11];
    const float* sk_bs  = (const float*)d_in[12];
    const float* o1w = (const float*)d_in[13];
    const float* o1b = (const float*)d_in[14];
    const float* o2w = (const float*)d_in[15];
    const float* o2b = (const float*)d_in[16];
    const float* o3w = (const float*)d_in[17];
    const float* o3b = (const float*)d_in[18];

    char* base = (char*)d_ws;
    float* X0   = (float*)(base);                      // 33554432 B
    float* X1   = (float*)(base + 33554432);
    float* SK   = (float*)(base + 67108864);
    short* Apk  = (short*)(base + 100663296);          // 11796480 B
    short* Spk  = (short*)(base + 112459776);          // 1966080 B
    float* o1T  = (float*)(base + 114425856);          // 65536 B
    float* o2T  = (float*)(base + 114491392);          // 65536 B
    float* a64  = (float*)(base + 114556928);          // 131072 B
    float* b64  = (float*)(base + 114688000);          // 131072 B
    float* x256 = (float*)(base + 114819072);          // 524288 B
    float* x1024= (float*)(base + 115343360);          // 2097152 B

    prep_w<<<27008, 256, 0, stream>>>(wn_wsp, sk_wsp, o1w, o2w, Apk, Spk, o1T, o2T);

    fe_in<<<dim3(64, 4), 128, 0, stream>>>(mel, in_w, in_b, a64);
    fe_pre<<<dim3(64, 4), 128, 0, stream>>>(a64, b64, pre_w + 0 * 49152, pre_b + 0 * 128, 1);
    fe_pre<<<dim3(64, 4), 128, 0, stream>>>(b64, a64, pre_w + 1 * 49152, pre_b + 1 * 128, 2);
    fe_pre<<<dim3(64, 4), 128, 0, stream>>>(a64, b64, pre_w + 2 * 49152, pre_b + 2 * 128, 4);
    fe_pre<<<dim3(64, 4), 128, 0, stream>>>(b64, a64, pre_w + 3 * 49152, pre_b + 3 * 128, 8);
    fe_pre<<<dim3(64, 4), 128, 0, stream>>>(a64, b64, pre_w + 4 * 49152, pre_b + 4 * 128, 16);
    fe_up<<<dim3(256, 4), 128, 0, stream>>>(b64, x256, up1_w, up1_b, 64);
    fe_up<<<dim3(1024, 4), 128, 0, stream>>>(x256, x1024, up2_w, up2_b, 256);
    fe_repeat<<<32768, 256, 0, stream>>>(x1024, X0, SK);

    float* xc = X0; float* xn = X1;
    for (int li = 0; li < 30; li++) {
        int d = 1 << (li % 10);
        wn_layer<<<dim3(T_LEN / 128, 4), 256, 0, stream>>>(
            xc, xn, SK,
            Apk + (size_t)li * 196608, wn_bs + li * 256,
            Spk + (size_t)li * 32768, sk_bs + li * 128, d);
        float* tmp = xc; xc = xn; xn = tmp;
    }

    os_conv<true><<<dim3(T_LEN / TT, 4), 256, 0, stream>>>(SK, X0, o1T, o1b);
    os_conv<false><<<dim3(T_LEN / TT, 4), 256, 0, stream>>>(X0, X1, o2T, o2b);
    os_final<<<256, 256, 0, stream>>>(X1, o3w, o3b, (float*)d_out);
}